// Round 1
// baseline (588.348 us; speedup 1.0000x reference)
//
#include <hip/hip_runtime.h>
#include <stdint.h>

// Problem constants
#define BATCH   16384
#define MEM_DIM 4096
#define FEAT    1024
#define LAMBD   0.00048828125f   // 2.0 / 4096
#define SEPS    1e-12f

typedef __attribute__((ext_vector_type(8))) short short8;
typedef __attribute__((ext_vector_type(4))) float f32x4;

__device__ __forceinline__ unsigned short f2bf(float x) {
  uint32_t u = __builtin_bit_cast(uint32_t, x);
  u += 0x7fffu + ((u >> 16) & 1u);   // round-to-nearest-even
  return (unsigned short)(u >> 16);
}
__device__ __forceinline__ float bf2f(unsigned short b) {
  uint32_t u = ((uint32_t)b) << 16;
  return __builtin_bit_cast(float, u);
}

// ---------------- cast f32 -> bf16, 8 elems/thread ----------------
__global__ __launch_bounds__(256) void cast_bf16_kernel(
    const float* __restrict__ in, unsigned short* __restrict__ out) {
  size_t i = ((size_t)blockIdx.x * blockDim.x + threadIdx.x) * 8;
  float4 a = *(const float4*)(in + i);
  float4 b = *(const float4*)(in + i + 4);
  union { unsigned short u[8]; short8 v; } r;
  r.u[0] = f2bf(a.x); r.u[1] = f2bf(a.y); r.u[2] = f2bf(a.z); r.u[3] = f2bf(a.w);
  r.u[4] = f2bf(b.x); r.u[5] = f2bf(b.y); r.u[6] = f2bf(b.z); r.u[7] = f2bf(b.w);
  *(short8*)(out + i) = r.v;
}

// ---------------- transpose + cast: memory[M][F] f32 -> memT[F][M] bf16 ----------------
__global__ __launch_bounds__(256) void transpose_cast_kernel(
    const float* __restrict__ in, unsigned short* __restrict__ out) {
  __shared__ unsigned short tile[32][33];
  const int mt = blockIdx.x;            // tile over MEM_DIM
  const int ct = blockIdx.y;            // tile over FEAT
  const int tx = threadIdx.x & 31;
  const int ty = threadIdx.x >> 5;      // 0..7
  #pragma unroll
  for (int r = ty; r < 32; r += 8)
    tile[r][tx] = f2bf(in[(size_t)(mt * 32 + r) * FEAT + ct * 32 + tx]);
  __syncthreads();
  #pragma unroll
  for (int r = ty; r < 32; r += 8)
    out[(size_t)(ct * 32 + r) * MEM_DIM + mt * 32 + tx] = tile[tx][r];
}

// ---------------- bt-GEMM: C[M,N] = A[M,K] * Bt[N,K]^T  (bf16 in, f32 acc) ----------------
// 128x128 tile, BK=32, 256 threads = 4 waves, each wave 64x64 (4x4 frags of 16x16x32)
template<bool OUT_BF16>
__global__ __launch_bounds__(256)
void gemm_bt(const unsigned short* __restrict__ A, const unsigned short* __restrict__ Bt,
             float* __restrict__ Cf, unsigned short* __restrict__ Cb,
             int K, int lda, int ldb, int ldc)
{
  __shared__ __align__(16) unsigned short sA[128 * 32];
  __shared__ __align__(16) unsigned short sB[128 * 32];

  const int tid  = threadIdx.x;
  const int lane = tid & 63;
  const int wave = tid >> 6;
  const int wr = wave >> 1, wc = wave & 1;
  const int bn = blockIdx.x, bm = blockIdx.y;
  const int lrow = lane & 15;
  const int lkg  = lane >> 4;

  f32x4 acc[4][4] = {};

  const size_t abase = (size_t)bm * 128 * lda;
  const size_t bbase = (size_t)bn * 128 * ldb;

  for (int k0 = 0; k0 < K; k0 += 32) {
    #pragma unroll
    for (int it = 0; it < 2; ++it) {
      const int chunk = it * 256 + tid;       // 512 x 16B chunks per 8KB tile
      const int row = chunk >> 2;
      const int col = (chunk & 3) * 8;
      __builtin_amdgcn_global_load_lds(
          (const __attribute__((address_space(1))) uint32_t*)(A + abase + (size_t)row * lda + k0 + col),
          (__attribute__((address_space(3))) uint32_t*)(sA + chunk * 8), 16, 0, 0);
      __builtin_amdgcn_global_load_lds(
          (const __attribute__((address_space(1))) uint32_t*)(Bt + bbase + (size_t)row * ldb + k0 + col),
          (__attribute__((address_space(3))) uint32_t*)(sB + chunk * 8), 16, 0, 0);
    }
    __syncthreads();   // drains vmcnt before use

    short8 af[4], bfr[4];
    #pragma unroll
    for (int i = 0; i < 4; ++i) {
      af[i]  = *(const short8*)&sA[(wr * 64 + i * 16 + lrow) * 32 + lkg * 8];
      bfr[i] = *(const short8*)&sB[(wc * 64 + i * 16 + lrow) * 32 + lkg * 8];
    }
    #pragma unroll
    for (int i = 0; i < 4; ++i)
      #pragma unroll
      for (int j = 0; j < 4; ++j)
        acc[i][j] = __builtin_amdgcn_mfma_f32_16x16x32_bf16(af[i], bfr[j], acc[i][j], 0, 0, 0);
    __syncthreads();
  }

  // Epilogue: C/D layout col=lane&15, row=(lane>>4)*4+reg  [guide-verified]
  const int row0 = bm * 128 + wr * 64 + (lane >> 4) * 4;
  const int col0 = bn * 128 + wc * 64 + (lane & 15);
  #pragma unroll
  for (int i = 0; i < 4; ++i)
    #pragma unroll
    for (int j = 0; j < 4; ++j)
      #pragma unroll
      for (int r = 0; r < 4; ++r) {
        const size_t row = row0 + i * 16 + r;
        const int col = col0 + j * 16;
        if (OUT_BF16) Cb[row * ldc + col] = f2bf(acc[i][j][r]);
        else          Cf[row * ldc + col] = acc[i][j][r];
      }
}

// ---------------- fused softmax -> hard_shrink_relu -> softmax, one block per row ----------------
__device__ __forceinline__ float block_reduce_max(float v, float* sred) {
  #pragma unroll
  for (int o = 32; o > 0; o >>= 1) v = fmaxf(v, __shfl_xor(v, o, 64));
  __syncthreads();                               // protect sred reuse
  if ((threadIdx.x & 63) == 0) sred[threadIdx.x >> 6] = v;
  __syncthreads();
  return fmaxf(fmaxf(sred[0], sred[1]), fmaxf(sred[2], sred[3]));
}
__device__ __forceinline__ float block_reduce_sum(float v, float* sred) {
  #pragma unroll
  for (int o = 32; o > 0; o >>= 1) v += __shfl_xor(v, o, 64);
  __syncthreads();
  if ((threadIdx.x & 63) == 0) sred[threadIdx.x >> 6] = v;
  __syncthreads();
  return (sred[0] + sred[1]) + (sred[2] + sred[3]);
}

__global__ __launch_bounds__(256)
void softmax_shrink_kernel(const unsigned short* __restrict__ W,  // [BATCH][MEM_DIM] bf16
                           float* __restrict__ att,               // [BATCH][MEM_DIM] f32 out
                           unsigned short* __restrict__ attb)     // bf16 out (in-place over W)
{
  __shared__ float sred[4];
  const int row = blockIdx.x;
  const int tid = threadIdx.x;
  const unsigned short* wrp = W + (size_t)row * MEM_DIM + tid * 16;

  union { short8 v; unsigned short u[8]; } l0, l1;
  l0.v = *(const short8*)wrp;
  l1.v = *(const short8*)(wrp + 8);
  float v[16];
  #pragma unroll
  for (int j = 0; j < 8; ++j) { v[j] = bf2f(l0.u[j]); v[8 + j] = bf2f(l1.u[j]); }

  // softmax 1
  float m = v[0];
  #pragma unroll
  for (int j = 1; j < 16; ++j) m = fmaxf(m, v[j]);
  m = block_reduce_max(m, sred);
  float s = 0.f, e[16];
  #pragma unroll
  for (int j = 0; j < 16; ++j) { e[j] = __expf(v[j] - m); s += e[j]; }
  const float inv1 = 1.f / block_reduce_sum(s, sred);

  // hard_shrink_relu: relu(p - l) * p / (|p - l| + eps)
  float wh[16];
  #pragma unroll
  for (int j = 0; j < 16; ++j) {
    const float p = e[j] * inv1;
    const float d = p - LAMBD;
    wh[j] = (d > 0.f) ? (d * p / (d + SEPS)) : 0.f;
  }

  // softmax 2
  float m2 = wh[0];
  #pragma unroll
  for (int j = 1; j < 16; ++j) m2 = fmaxf(m2, wh[j]);
  m2 = block_reduce_max(m2, sred);
  float s2 = 0.f, a[16];
  #pragma unroll
  for (int j = 0; j < 16; ++j) { a[j] = __expf(wh[j] - m2); s2 += a[j]; }
  const float inv2 = 1.f / block_reduce_sum(s2, sred);

  float* arow = att + (size_t)row * MEM_DIM + tid * 16;
  #pragma unroll
  for (int j = 0; j < 16; j += 4) {
    float4 o; o.x = a[j] * inv2; o.y = a[j+1] * inv2; o.z = a[j+2] * inv2; o.w = a[j+3] * inv2;
    *(float4*)(arow + j) = o;
  }
  union { short8 v; unsigned short u[8]; } s0, s1;
  #pragma unroll
  for (int j = 0; j < 8; ++j) { s0.u[j] = f2bf(a[j] * inv2); s1.u[j] = f2bf(a[8 + j] * inv2); }
  unsigned short* ab = attb + (size_t)row * MEM_DIM + tid * 16;
  *(short8*)ab = s0.v;
  *(short8*)(ab + 8) = s1.v;
}

// ---------------- launcher ----------------
extern "C" void kernel_launch(void* const* d_in, const int* in_sizes, int n_in,
                              void* d_out, int out_size, void* d_ws, size_t ws_size,
                              hipStream_t stream) {
  const float* z   = (const float*)d_in[0];   // [16384, 1024]
  const float* mem = (const float*)d_in[1];   // [4096, 1024]
  float* att_out  = (float*)d_out;                              // [16384*4096]
  float* zhat_out = (float*)d_out + (size_t)BATCH * MEM_DIM;    // [16384*1024]

  // workspace layout (needs ~185 MB)
  unsigned short* zb    = (unsigned short*)d_ws;                 // 16384*1024 bf16
  unsigned short* memb  = zb + (size_t)BATCH * FEAT;             // 4096*1024
  unsigned short* membT = memb + (size_t)MEM_DIM * FEAT;         // 1024*4096
  unsigned short* wbuf  = membT + (size_t)FEAT * MEM_DIM;        // 16384*4096 (w, then att bf16 in-place)

  // casts
  cast_bf16_kernel<<<(BATCH * FEAT / 8) / 256, 256, 0, stream>>>(z, zb);
  cast_bf16_kernel<<<(MEM_DIM * FEAT / 8) / 256, 256, 0, stream>>>(mem, memb);
  transpose_cast_kernel<<<dim3(MEM_DIM / 32, FEAT / 32), 256, 0, stream>>>(mem, membT);

  // GEMM1: w = z @ mem^T   [16384,4096], K=1024 -> bf16 out
  gemm_bt<true><<<dim3(MEM_DIM / 128, BATCH / 128), 256, 0, stream>>>(
      zb, memb, nullptr, wbuf, FEAT, FEAT, FEAT, MEM_DIM);

  // fused double-softmax + hardshrink; att f32 to d_out, att bf16 in-place into wbuf
  softmax_shrink_kernel<<<BATCH, 256, 0, stream>>>(wbuf, att_out, wbuf);

  // GEMM2: z_hat = att @ mem = att @ (memT)^T   [16384,1024], K=4096 -> f32 out
  gemm_bt<false><<<dim3(FEAT / 128, BATCH / 128), 256, 0, stream>>>(
      wbuf, membT, zhat_out, nullptr, MEM_DIM, MEM_DIM, MEM_DIM, FEAT);
}

// Round 2
// 394.441 us; speedup vs baseline: 1.4916x; 1.4916x over previous
//
#include <hip/hip_runtime.h>
#include <stdint.h>

// Problem constants
#define BATCH   16384
#define MEM_DIM 4096
#define FEAT    1024
#define LAMBD   0.00048828125f   // 2.0 / 4096
#define SEPS    1e-12f

typedef __attribute__((ext_vector_type(8))) short short8;
typedef __attribute__((ext_vector_type(4))) float f32x4;

__device__ __forceinline__ unsigned short f2bf(float x) {
  uint32_t u = __builtin_bit_cast(uint32_t, x);
  u += 0x7fffu + ((u >> 16) & 1u);   // round-to-nearest-even
  return (unsigned short)(u >> 16);
}
__device__ __forceinline__ float bf2f(unsigned short b) {
  uint32_t u = ((uint32_t)b) << 16;
  return __builtin_bit_cast(float, u);
}

// ---------------- cast f32 -> bf16, 8 elems/thread ----------------
__global__ __launch_bounds__(256) void cast_bf16_kernel(
    const float* __restrict__ in, unsigned short* __restrict__ out) {
  size_t i = ((size_t)blockIdx.x * blockDim.x + threadIdx.x) * 8;
  float4 a = *(const float4*)(in + i);
  float4 b = *(const float4*)(in + i + 4);
  union { unsigned short u[8]; short8 v; } r;
  r.u[0] = f2bf(a.x); r.u[1] = f2bf(a.y); r.u[2] = f2bf(a.z); r.u[3] = f2bf(a.w);
  r.u[4] = f2bf(b.x); r.u[5] = f2bf(b.y); r.u[6] = f2bf(b.z); r.u[7] = f2bf(b.w);
  *(short8*)(out + i) = r.v;
}

// ---------------- transpose + cast: memory[M][F] f32 -> memT[F][M] bf16 ----------------
__global__ __launch_bounds__(256) void transpose_cast_kernel(
    const float* __restrict__ in, unsigned short* __restrict__ out) {
  __shared__ unsigned short tile[32][33];
  const int mt = blockIdx.x;
  const int ct = blockIdx.y;
  const int tx = threadIdx.x & 31;
  const int ty = threadIdx.x >> 5;
  #pragma unroll
  for (int r = ty; r < 32; r += 8)
    tile[r][tx] = f2bf(in[(size_t)(mt * 32 + r) * FEAT + ct * 32 + tx]);
  __syncthreads();
  #pragma unroll
  for (int r = ty; r < 32; r += 8)
    out[(size_t)(ct * 32 + r) * MEM_DIM + mt * 32 + tx] = tile[tx][r];
}

// =====================================================================
// 256x256 8-phase bt-GEMM: C[M,N] = A[M,K] * Bt[N,K]^T  (bf16 in, f32 acc)
// 512 threads = 8 waves (2M x 4N), BK=64, 2 K-tiles/iter, 8 phases/iter.
// LDS 128KB: [dbuf][A|B][half 128x64] st_16x32-swizzled subtiled layout.
// =====================================================================

#define LDSB(db, ab, h) ((((db)*2 + (ab))*2 + (h)) * 16384)

#define CFENCE asm volatile("" ::: "memory")
#define BAR()  do { CFENCE; __builtin_amdgcn_s_barrier(); CFENCE; } while (0)
#define LGKM0  asm volatile("s_waitcnt lgkmcnt(0)" ::: "memory")
#define VM4    asm volatile("s_waitcnt vmcnt(4)" ::: "memory")

// stage one 128x64 half-tile (16KB) = 2 x global_load_lds(16B) per thread.
// LDS dest is linear (chunk c at byte c*16); global source is inverse-swizzled.
#define STAGE(src, base, h, db, ab, kb) do {                                        \
    __builtin_amdgcn_global_load_lds(                                               \
      (const __attribute__((address_space(1))) uint32_t*)((src) + (base) +          \
          (size_t)(h) * 128 * K + rel0 + (kb)),                                     \
      (__attribute__((address_space(3))) uint32_t*)(lds + LDSB(db, ab, h) + tid*16),\
      16, 0, 0);                                                                    \
    __builtin_amdgcn_global_load_lds(                                               \
      (const __attribute__((address_space(1))) uint32_t*)((src) + (base) +          \
          (size_t)(h) * 128 * K + rel1 + (kb)),                                     \
      (__attribute__((address_space(3))) uint32_t*)(lds + LDSB(db, ab, h) + 8192 +  \
          tid*16),                                                                  \
      16, 0, 0);                                                                    \
  } while (0)

#define RD_A(db, mh)                                                                \
  _Pragma("unroll") for (int mi = 0; mi < 4; ++mi) {                                \
    _Pragma("unroll") for (int kk = 0; kk < 2; ++kk)                                \
      af[mi][kk] = *(const short8*)(aP##db + ((mh) << 13) + (mi << 11) + (kk << 10)); \
  }

#define RD_B2(db, n0)                                                               \
  _Pragma("unroll") for (int ni = 0; ni < 2; ++ni) {                                \
    _Pragma("unroll") for (int kk = 0; kk < 2; ++kk)                                \
      bfr[(n0) + ni][kk] = *(const short8*)(bP##db + (((n0) + ni) << 11) + (kk << 10)); \
  }

#define MFMA_Q(mh, nh) do {                                                         \
    __builtin_amdgcn_s_setprio(1);                                                  \
    _Pragma("unroll") for (int mi = 0; mi < 4; ++mi)                                \
    _Pragma("unroll") for (int ni = 0; ni < 2; ++ni)                                \
    _Pragma("unroll") for (int kk = 0; kk < 2; ++kk)                                \
      acc[(mh)*4 + mi][(nh)*2 + ni] = __builtin_amdgcn_mfma_f32_16x16x32_bf16(      \
          af[mi][kk], bfr[(nh)*2 + ni][kk], acc[(mh)*4 + mi][(nh)*2 + ni], 0, 0, 0);\
    __builtin_amdgcn_s_setprio(0);                                                  \
  } while (0)

template<bool OUT_BF16>
__global__ __launch_bounds__(512, 2)
void gemm256(const unsigned short* __restrict__ A, const unsigned short* __restrict__ Bt,
             float* __restrict__ Cf, unsigned short* __restrict__ Cb,
             const int K, const int ldc, const int nbn)
{
  __shared__ __align__(16) char lds[131072];

  const int tid  = threadIdx.x;
  const int lane = tid & 63;
  const int wid  = tid >> 6;
  const int wm = wid >> 2;       // 0..1
  const int wn = wid & 3;        // 0..3
  const int lrow = lane & 15;
  const int lkg  = lane >> 4;

  // XCD-aware bijective block swizzle (nwg % 8 == 0 for both GEMMs)
  const int nwg = (int)gridDim.x;
  int wg = (int)blockIdx.x;
  wg = (wg & 7) * (nwg >> 3) + (wg >> 3);
  const int bm = wg / nbn;
  const int bn = wg % nbn;

  // ---- staging source offsets: invert st_16x32 swizzle for linear LDS dest ----
  size_t rel0, rel1;
  {
    #pragma unroll
    for (int j = 0; j < 2; ++j) {
      const int c = j * 512 + tid;
      const int d = c * 16;              // linear byte offset in 16KB half
      const int s = d >> 10;             // 1KB subtile index
      int w = d & 1023;
      w ^= ((w >> 9) & 1) << 5;          // involution
      const int row  = ((s >> 1) << 4) + (w >> 6);
      const int colE = ((s & 1) << 5) + ((w & 63) >> 1);
      const size_t r = (size_t)row * K + colE;
      if (j == 0) rel0 = r; else rel1 = r;
    }
  }
  const size_t baseA = (size_t)bm * 256 * K;
  const size_t baseB = (size_t)bn * 256 * K;

  // per-lane swizzled LDS read base (bytes within a half)
  const int lane_base = (((lrow << 6) | (lkg << 4)) ^ ((((lrow >> 3) & 1)) << 5));
  const char* aP0 = lds + LDSB(0, 0, 0) + wm * 16384 + lane_base;
  const char* aP1 = lds + LDSB(1, 0, 0) + wm * 16384 + lane_base;
  const char* bP0 = lds + LDSB(0, 1, 0) + (wn >> 1) * 16384 + ((wn & 1) << 13) + lane_base;
  const char* bP1 = lds + LDSB(1, 1, 0) + (wn >> 1) * 16384 + ((wn & 1) << 13) + lane_base;

  f32x4 acc[8][4] = {};
  short8 af[4][2], bfr[4][2];

  const int NT  = K >> 6;   // K-tiles of 64
  const int NIT = K >> 7;   // iterations (2 K-tiles each)

  // ---- prologue: dbuf0 <- tile0 (A+B), dbuf1 <- tile1 (B only; A staged in P1/P2) ----
  STAGE(A,  baseA, 0, 0, 0, 0);
  STAGE(A,  baseA, 1, 0, 0, 0);
  STAGE(Bt, baseB, 0, 0, 1, 0);
  STAGE(Bt, baseB, 1, 0, 1, 0);
  STAGE(Bt, baseB, 0, 1, 1, 64);
  STAGE(Bt, baseB, 1, 1, 1, 64);
  VM4;       // first 8 loads (dbuf0 tile0) landed; dbuf1-B may remain in flight
  BAR();

  for (int it = 0; it < NIT; ++it) {
    const int t2 = 2 * it + 2, t3 = 2 * it + 3;
    const int kb1 = (2 * it + 1) * 64;
    const int kb2 = (t2 < NT) ? t2 * 64 : 0;   // tail: stage valid-but-unused data
    const int kb3 = (t3 < NT) ? t3 * 64 : 0;

    // ---- phases 1-4: compute dbuf0 (K-tile 2it) ----
    // P1: Q(0,0)
    RD_A(0, 0); RD_B2(0, 0);
    STAGE(A, baseA, 0, 1, 0, kb1);            // dbuf1 A-h0 (tile 2it+1)
    BAR(); LGKM0; MFMA_Q(0, 0); BAR();
    // P2: Q(0,1)
    RD_B2(0, 2);
    STAGE(A, baseA, 1, 1, 0, kb1);            // dbuf1 A-h1
    BAR(); LGKM0; MFMA_Q(0, 1); BAR();
    // P3: Q(1,0)
    RD_A(0, 1);
    STAGE(Bt, baseB, 0, 0, 1, kb2);           // dbuf0 B-h0 (tile 2it+2); B reads done @P2
    BAR(); LGKM0; MFMA_Q(1, 0); BAR();
    // P4: Q(1,1)
    STAGE(Bt, baseB, 1, 0, 1, kb2);           // dbuf0 B-h1
    BAR(); LGKM0; MFMA_Q(1, 1); VM4; BAR();   // dbuf1 (A@P1/P2 + B@P7/P8 prev) landed

    // ---- phases 5-8: compute dbuf1 (K-tile 2it+1) ----
    // P5: Q(0,0)
    RD_A(1, 0); RD_B2(1, 0);
    STAGE(A, baseA, 0, 0, 0, kb2);            // dbuf0 A-h0 (tile 2it+2); A reads done @P3
    BAR(); LGKM0; MFMA_Q(0, 0); BAR();
    // P6: Q(0,1)
    RD_B2(1, 2);
    STAGE(A, baseA, 1, 0, 0, kb2);            // dbuf0 A-h1
    BAR(); LGKM0; MFMA_Q(0, 1); BAR();
    // P7: Q(1,0)
    RD_A(1, 1);
    STAGE(Bt, baseB, 0, 1, 1, kb3);           // dbuf1 B-h0 (tile 2it+3); B reads done @P6
    BAR(); LGKM0; MFMA_Q(1, 0); BAR();
    // P8: Q(1,1)
    STAGE(Bt, baseB, 1, 1, 1, kb3);           // dbuf1 B-h1
    BAR(); LGKM0; MFMA_Q(1, 1); VM4; BAR();   // dbuf0 (B@P3/P4 + A@P5/P6) landed
  }

  // ---- epilogue: C/D layout col=lane&15, row=(lane>>4)*4+reg ----
  const int row0 = bm * 256 + wm * 128 + lkg * 4;
  const int col0 = bn * 256 + wn * 64 + lrow;
  #pragma unroll
  for (int mi = 0; mi < 8; ++mi)
    #pragma unroll
    for (int ni = 0; ni < 4; ++ni)
      #pragma unroll
      for (int r = 0; r < 4; ++r) {
        const size_t row = row0 + mi * 16 + r;
        const int col = col0 + ni * 16;
        if (OUT_BF16) Cb[row * ldc + col] = f2bf(acc[mi][ni][r]);
        else          Cf[row * ldc + col] = acc[mi][ni][r];
      }
}

// ---------------- fused softmax -> hard_shrink_relu -> softmax, one block per row ----------------
__device__ __forceinline__ float block_reduce_max(float v, float* sred) {
  #pragma unroll
  for (int o = 32; o > 0; o >>= 1) v = fmaxf(v, __shfl_xor(v, o, 64));
  __syncthreads();
  if ((threadIdx.x & 63) == 0) sred[threadIdx.x >> 6] = v;
  __syncthreads();
  return fmaxf(fmaxf(sred[0], sred[1]), fmaxf(sred[2], sred[3]));
}
__device__ __forceinline__ float block_reduce_sum(float v, float* sred) {
  #pragma unroll
  for (int o = 32; o > 0; o >>= 1) v += __shfl_xor(v, o, 64);
  __syncthreads();
  if ((threadIdx.x & 63) == 0) sred[threadIdx.x >> 6] = v;
  __syncthreads();
  return (sred[0] + sred[1]) + (sred[2] + sred[3]);
}

__global__ __launch_bounds__(256)
void softmax_shrink_kernel(const unsigned short* __restrict__ W,
                           float* __restrict__ att,
                           unsigned short* __restrict__ attb)
{
  __shared__ float sred[4];
  const int row = blockIdx.x;
  const int tid = threadIdx.x;
  const unsigned short* wrp = W + (size_t)row * MEM_DIM + tid * 16;

  union { short8 v; unsigned short u[8]; } l0, l1;
  l0.v = *(const short8*)wrp;
  l1.v = *(const short8*)(wrp + 8);
  float v[16];
  #pragma unroll
  for (int j = 0; j < 8; ++j) { v[j] = bf2f(l0.u[j]); v[8 + j] = bf2f(l1.u[j]); }

  float m = v[0];
  #pragma unroll
  for (int j = 1; j < 16; ++j) m = fmaxf(m, v[j]);
  m = block_reduce_max(m, sred);
  float s = 0.f, e[16];
  #pragma unroll
  for (int j = 0; j < 16; ++j) { e[j] = __expf(v[j] - m); s += e[j]; }
  const float inv1 = 1.f / block_reduce_sum(s, sred);

  float wh[16];
  #pragma unroll
  for (int j = 0; j < 16; ++j) {
    const float p = e[j] * inv1;
    const float d = p - LAMBD;
    wh[j] = (d > 0.f) ? (d * p / (d + SEPS)) : 0.f;
  }

  float m2 = wh[0];
  #pragma unroll
  for (int j = 1; j < 16; ++j) m2 = fmaxf(m2, wh[j]);
  m2 = block_reduce_max(m2, sred);
  float s2 = 0.f, a[16];
  #pragma unroll
  for (int j = 0; j < 16; ++j) { a[j] = __expf(wh[j] - m2); s2 += a[j]; }
  const float inv2 = 1.f / block_reduce_sum(s2, sred);

  float* arow = att + (size_t)row * MEM_DIM + tid * 16;
  #pragma unroll
  for (int j = 0; j < 16; j += 4) {
    float4 o; o.x = a[j] * inv2; o.y = a[j+1] * inv2; o.z = a[j+2] * inv2; o.w = a[j+3] * inv2;
    *(float4*)(arow + j) = o;
  }
  union { short8 v; unsigned short u[8]; } s0, s1;
  #pragma unroll
  for (int j = 0; j < 8; ++j) { s0.u[j] = f2bf(a[j] * inv2); s1.u[j] = f2bf(a[8 + j] * inv2); }
  unsigned short* ab = attb + (size_t)row * MEM_DIM + tid * 16;
  *(short8*)ab = s0.v;
  *(short8*)(ab + 8) = s1.v;
}

// ---------------- launcher ----------------
extern "C" void kernel_launch(void* const* d_in, const int* in_sizes, int n_in,
                              void* d_out, int out_size, void* d_ws, size_t ws_size,
                              hipStream_t stream) {
  const float* z   = (const float*)d_in[0];   // [16384, 1024]
  const float* mem = (const float*)d_in[1];   // [4096, 1024]
  float* att_out  = (float*)d_out;
  float* zhat_out = (float*)d_out + (size_t)BATCH * MEM_DIM;

  unsigned short* zb    = (unsigned short*)d_ws;
  unsigned short* memb  = zb + (size_t)BATCH * FEAT;
  unsigned short* membT = memb + (size_t)MEM_DIM * FEAT;
  unsigned short* wbuf  = membT + (size_t)FEAT * MEM_DIM;

  cast_bf16_kernel<<<(BATCH * FEAT / 8) / 256, 256, 0, stream>>>(z, zb);
  cast_bf16_kernel<<<(MEM_DIM * FEAT / 8) / 256, 256, 0, stream>>>(mem, memb);
  transpose_cast_kernel<<<dim3(MEM_DIM / 32, FEAT / 32), 256, 0, stream>>>(mem, membT);

  // GEMM1: w = z @ mem^T   [16384,4096], K=1024 -> bf16
  gemm256<true><<<(MEM_DIM / 256) * (BATCH / 256), 512, 0, stream>>>(
      zb, memb, nullptr, wbuf, FEAT, MEM_DIM, MEM_DIM / 256);

  softmax_shrink_kernel<<<BATCH, 256, 0, stream>>>(wbuf, att_out, wbuf);

  // GEMM2: z_hat = att @ mem = att @ (memT)^T   [16384,1024], K=4096 -> f32
  gemm256<false><<<(FEAT / 256) * (BATCH / 256), 512, 0, stream>>>(
      wbuf, membT, zhat_out, nullptr, MEM_DIM, FEAT, FEAT / 256);
}